// Round 5
// baseline (709.147 us; speedup 1.0000x reference)
//
#include <hip/hip_runtime.h>
#include <hip/hip_bf16.h>
#include <hip/hip_cooperative_groups.h>

namespace cg = cooperative_groups;

#define NPTS 262144
#define DIM  128
#define KC   20
#define MP   10
#define LNEPS 1e-5f
#define EPSI  0.05f
#define CCAP  65536
#define EPITCH 210

typedef _Float16 half8 __attribute__((ext_vector_type(8)));
typedef float f32x4 __attribute__((ext_vector_type(4)));

union H8U4 { half8 h; uint4 u; };

// workspace layout (float offsets)
#define WS_PN     0          // 25600 normalized protos f32
#define WS_PHI    25600      // 13312 floats (208x128 f16 hi)
#define WS_PLO    38912      // 13312 floats (f16 lo)
#define WS_F      52224      // 25600 f accumulator
#define WS_NCOUNT 77824      // 200
#define WS_CCNT   78024      // 8 (int counter + pad)
#define WS_UH     78032      // 600 u history (3 x 200)
#define WS_SK     78632      // 20
#define WS_BC     78652      // 20
#define WS_PSB    78672      // 40*4096 partials
#define WS_PR     242512     // 200*256 row-sum partials
#define WS_EXPV   293712     // N*12 (10 + 2 pad)
#define WS_CIDX   3439440    // 65536 ints
// total 3504976 floats = 14.0 MB

__device__ __forceinline__ half8 lds_h8(const uint4* p) {
    return *reinterpret_cast<const half8*>(p);
}

// ---- normalize prototypes, emit f32 + f16 hi/lo (rows 200..207 zero-padded)
__global__ __launch_bounds__(64) void k_norm_protos(
    const float* __restrict__ pr, float* __restrict__ pn,
    _Float16* __restrict__ phi, _Float16* __restrict__ plo)
{
    int j = blockIdx.x, l = threadIdx.x;
    if (j < 200) {
        float x0 = pr[(size_t)j*128 + l], x1 = pr[(size_t)j*128 + 64 + l];
        float ss = x0*x0 + x1*x1;
        #pragma unroll
        for (int off = 32; off > 0; off >>= 1) ss += __shfl_xor(ss, off);
        float dn = fmaxf(sqrtf(ss), 1e-12f);
        float y0 = x0/dn, y1 = x1/dn;
        pn[(size_t)j*128 + l]      = y0;
        pn[(size_t)j*128 + 64 + l] = y1;
        _Float16 h0 = (_Float16)y0, h1 = (_Float16)y1;
        phi[(size_t)j*128 + l]      = h0;
        phi[(size_t)j*128 + 64 + l] = h1;
        plo[(size_t)j*128 + l]      = (_Float16)(y0 - (float)h0);
        plo[(size_t)j*128 + 64 + l] = (_Float16)(y1 - (float)h1);
    } else {
        phi[(size_t)j*128 + l] = (_Float16)0.f;  phi[(size_t)j*128 + 64 + l] = (_Float16)0.f;
        plo[(size_t)j*128 + l] = (_Float16)0.f;  plo[(size_t)j*128 + 64 + l] = (_Float16)0.f;
    }
}

// ---- GEMM-only kernel. Grid 256 x 512 thr (8 waves). B staged once in LDS;
//  main loop has ZERO barriers (waves drift). MFMA operands swapped so each
//  lane holds 4 consecutive proto cols -> float4 plog stores.
__global__ __launch_bounds__(512, 2) void k_gemm(
    const float* __restrict__ feat,
    const _Float16* __restrict__ phi, const _Float16* __restrict__ plo,
    const float* __restrict__ fg, const float* __restrict__ fb,
    float* __restrict__ plog)
{
    __shared__ __align__(16) char lds[106496];
    uint4* bHi = (uint4*)lds;                       // 3328 uint4
    uint4* bLo = (uint4*)(lds + 53248);

    const int t = threadIdx.x;
    const int w = t >> 6, lane = t & 63;
    const int l15 = lane & 15, l4 = lane >> 4;

    // ---- stage full B (swizzled slot = s ^ (row&15)), once per block
    {
        const uint4* phi4 = (const uint4*)phi;
        const uint4* plo4 = (const uint4*)plo;
        #pragma unroll
        for (int ii = 0; ii < 13; ++ii) {
            int idx = ii*512 + t;
            bool ishi = idx < 3328;
            int ridx = ishi ? idx : idx - 3328;
            int dst = (ridx & ~15) | ((ridx & 15) ^ ((ridx >> 4) & 15));
            uint4 vv = ishi ? phi4[ridx] : plo4[ridx];
            (ishi ? bHi : bLo)[dst] = vv;
        }
    }
    __syncthreads();   // only barrier in the kernel

    const float4* gfeat = (const float4*)feat;

    #pragma unroll 1
    for (int ch = 0; ch < 4; ++ch) {
        const int pbase = (ch*256 + blockIdx.x) * 256;

        // ---- A direct loads in fragment layout: row = pbase+w*32+mt*16+l15
        float4 A[2][4][2];
        #pragma unroll
        for (int mt = 0; mt < 2; ++mt) {
            size_t rb = (size_t)(pbase + w*32 + mt*16 + l15) * 32;
            #pragma unroll
            for (int kst = 0; kst < 4; ++kst)
                #pragma unroll
                for (int h = 0; h < 2; ++h)
                    A[mt][kst][h] = gfeat[rb + kst*8 + l4*2 + h];
        }
        float4 G[4][2], Bb[4][2];
        {
            const float4* fg4 = (const float4*)fg;
            const float4* fb4 = (const float4*)fb;
            #pragma unroll
            for (int kst = 0; kst < 4; ++kst)
                #pragma unroll
                for (int h = 0; h < 2; ++h) {
                    G[kst][h]  = fg4[kst*8 + l4*2 + h];
                    Bb[kst][h] = fb4[kst*8 + l4*2 + h];
                }
        }

        // ---- LN + l2n per mt (4-lane group reduce over lanes {l15,+16,+32,+48})
        half8 fah[2][4], fal[2][4];
        #pragma unroll
        for (int mt = 0; mt < 2; ++mt) {
            float s0 = 0.f;
            #pragma unroll
            for (int kst = 0; kst < 4; ++kst)
                #pragma unroll
                for (int h = 0; h < 2; ++h) {
                    float4 v = A[mt][kst][h];
                    s0 += v.x + v.y + v.z + v.w;
                }
            s0 += __shfl_xor(s0, 16); s0 += __shfl_xor(s0, 32);
            float mean = s0 * (1.f/128.f);
            float s1 = 0.f;
            #pragma unroll
            for (int kst = 0; kst < 4; ++kst)
                #pragma unroll
                for (int h = 0; h < 2; ++h) {
                    float4 v = A[mt][kst][h];
                    float a = v.x-mean, b = v.y-mean, c = v.z-mean, d = v.w-mean;
                    s1 += a*a + b*b + c*c + d*d;
                }
            s1 += __shfl_xor(s1, 16); s1 += __shfl_xor(s1, 32);
            float rstd = rsqrtf(s1 * (1.f/128.f) + LNEPS);
            float s2 = 0.f;
            #pragma unroll
            for (int kst = 0; kst < 4; ++kst)
                #pragma unroll
                for (int h = 0; h < 2; ++h) {
                    float4 v = A[mt][kst][h];
                    float4 g = G[kst][h], bb = Bb[kst][h];
                    v.x = (v.x-mean)*rstd*g.x + bb.x;
                    v.y = (v.y-mean)*rstd*g.y + bb.y;
                    v.z = (v.z-mean)*rstd*g.z + bb.z;
                    v.w = (v.w-mean)*rstd*g.w + bb.w;
                    A[mt][kst][h] = v;
                    s2 += v.x*v.x + v.y*v.y + v.z*v.z + v.w*v.w;
                }
            s2 += __shfl_xor(s2, 16); s2 += __shfl_xor(s2, 32);
            float rl2 = 1.f / fmaxf(sqrtf(s2), 1e-12f);
            #pragma unroll
            for (int kst = 0; kst < 4; ++kst) {
                float4 va = A[mt][kst][0], vb = A[mt][kst][1];
                va.x*=rl2; va.y*=rl2; va.z*=rl2; va.w*=rl2;
                vb.x*=rl2; vb.y*=rl2; vb.z*=rl2; vb.w*=rl2;
                H8U4 h, lo;
                h.h[0]=(_Float16)va.x; h.h[1]=(_Float16)va.y; h.h[2]=(_Float16)va.z; h.h[3]=(_Float16)va.w;
                h.h[4]=(_Float16)vb.x; h.h[5]=(_Float16)vb.y; h.h[6]=(_Float16)vb.z; h.h[7]=(_Float16)vb.w;
                lo.h[0]=(_Float16)(va.x-(float)h.h[0]); lo.h[1]=(_Float16)(va.y-(float)h.h[1]);
                lo.h[2]=(_Float16)(va.z-(float)h.h[2]); lo.h[3]=(_Float16)(va.w-(float)h.h[3]);
                lo.h[4]=(_Float16)(vb.x-(float)h.h[4]); lo.h[5]=(_Float16)(vb.y-(float)h.h[5]);
                lo.h[6]=(_Float16)(vb.z-(float)h.h[6]); lo.h[7]=(_Float16)(vb.w-(float)h.h[7]);
                fah[mt][kst] = h.h;
                fal[mt][kst] = lo.h;
            }
        }

        // ---- barrier-free MFMA GEMM, swapped operands: D[row=proto][col=point]
        f32x4 acc[2][13];
        #pragma unroll
        for (int mt = 0; mt < 2; ++mt)
            #pragma unroll
            for (int nt = 0; nt < 13; ++nt)
                acc[mt][nt] = (f32x4){0.f,0.f,0.f,0.f};

        #pragma unroll
        for (int nt = 0; nt < 13; ++nt) {
            const uint4* bH = bHi + (nt*16 + l15)*16;
            const uint4* bL = bLo + (nt*16 + l15)*16;
            #pragma unroll
            for (int kst = 0; kst < 4; ++kst) {
                int sl = (kst*4 + l4) ^ l15;
                half8 bh = lds_h8(bH + sl);
                half8 bl = lds_h8(bL + sl);
                acc[0][nt] = __builtin_amdgcn_mfma_f32_16x16x32_f16(bh, fah[0][kst], acc[0][nt], 0,0,0);
                acc[0][nt] = __builtin_amdgcn_mfma_f32_16x16x32_f16(bh, fal[0][kst], acc[0][nt], 0,0,0);
                acc[0][nt] = __builtin_amdgcn_mfma_f32_16x16x32_f16(bl, fah[0][kst], acc[0][nt], 0,0,0);
                acc[0][nt] = __builtin_amdgcn_mfma_f32_16x16x32_f16(bl, fal[0][kst], acc[0][nt], 0,0,0);
                acc[1][nt] = __builtin_amdgcn_mfma_f32_16x16x32_f16(bh, fah[1][kst], acc[1][nt], 0,0,0);
                acc[1][nt] = __builtin_amdgcn_mfma_f32_16x16x32_f16(bh, fal[1][kst], acc[1][nt], 0,0,0);
                acc[1][nt] = __builtin_amdgcn_mfma_f32_16x16x32_f16(bl, fah[1][kst], acc[1][nt], 0,0,0);
                acc[1][nt] = __builtin_amdgcn_mfma_f32_16x16x32_f16(bl, fal[1][kst], acc[1][nt], 0,0,0);
            }
        }

        // ---- plog float4 stores: lane l15 = point, cols nt*16 + l4*4 + {0..3}
        #pragma unroll
        for (int mt = 0; mt < 2; ++mt)
            #pragma unroll
            for (int nt = 0; nt < 13; ++nt)
                if (nt < 12 || l4 < 2) {
                    float4 vv;
                    vv.x = acc[mt][nt][0]; vv.y = acc[mt][nt][1];
                    vv.z = acc[mt][nt][2]; vv.w = acc[mt][nt][3];
                    *reinterpret_cast<float4*>(
                        &plog[(size_t)(pbase + w*32 + mt*16 + l15)*200 + nt*16 + l4*4]) = vv;
                }
    }
}

// ---- epilogue kernel: read plog (L3-warm), out_seg LN, pred/correct, expv, partials
__global__ __launch_bounds__(256, 2) void k_epi(
    const float* __restrict__ plog, const int* __restrict__ gt,
    const float* __restrict__ mg, const float* __restrict__ mb,
    float* __restrict__ out_seg, float* __restrict__ expv,
    float* __restrict__ psb, int* __restrict__ cidx, int* __restrict__ ccnt)
{
    __shared__ __align__(16) float llds[64*EPITCH];
    __shared__ float sumS[64];
    __shared__ int   gtS[64];
    const int t = threadIdx.x, blk = blockIdx.x, base = blk*64;
    const float* src = plog + (size_t)base*200;
    #pragma unroll
    for (int ii = 0; ii < 50; ++ii) {
        int f = ii*256 + t;
        llds[(f/200)*EPITCH + (f%200)] = src[f];
    }
    __syncthreads();
    const int q = t >> 2, sub = t & 3;
    const int n = base + q;
    float ml[5];
    #pragma unroll
    for (int kk = 0; kk < 5; ++kk) {
        int k = sub*5 + kk;
        float mx = llds[q*EPITCH + k*10];
        #pragma unroll
        for (int m = 1; m < 10; ++m) mx = fmaxf(mx, llds[q*EPITCH + k*10 + m]);
        ml[kk] = mx;
    }
    float s0 = ml[0]+ml[1]+ml[2]+ml[3]+ml[4];
    s0 += __shfl_xor(s0,1); s0 += __shfl_xor(s0,2);
    float mean = s0 / 20.f;
    float s1 = 0.f;
    #pragma unroll
    for (int kk = 0; kk < 5; ++kk) { float d = ml[kk]-mean; s1 += d*d; }
    s1 += __shfl_xor(s1,1); s1 += __shfl_xor(s1,2);
    float rstd = rsqrtf(s1 / 20.f + LNEPS);
    float bv = -1e30f; int bk = 0;
    #pragma unroll
    for (int kk = 0; kk < 5; ++kk) {
        int k = sub*5 + kk;
        float y = (ml[kk]-mean)*rstd*mg[k] + mb[k];
        out_seg[(size_t)n*20 + k] = y;
        if (y > bv) { bv = y; bk = k; }
    }
    #pragma unroll
    for (int off = 1; off <= 2; off <<= 1) {   // first-max-wins merge
        float ov = __shfl_xor(bv, off);
        int   ok = __shfl_xor(bk, off);
        if (ov > bv || (ov == bv && ok < bk)) { bv = ov; bk = ok; }
    }
    int g = gt[n];
    if (sub == 0) {
        if (bk == g) {
            int slot = atomicAdd(ccnt, 1);
            if (slot < CCAP) cidx[slot] = n;
        }
        float se = 0.f;
        #pragma unroll
        for (int m = 0; m < 10; ++m) {
            float e = expf(llds[q*EPITCH + g*10 + m] / EPSI);
            expv[(size_t)n*12 + m] = e;
            se += e;
        }
        sumS[q] = se;
        gtS[q] = g;
    }
    __syncthreads();
    if (t < 20) {
        float cnt = 0.f, s = 0.f;
        for (int p = 0; p < 64; ++p)
            if (gtS[p] == t) { cnt += 1.f; s += sumS[p]; }
        psb[(size_t)t*4096 + blk]      = cnt;
        psb[(size_t)(20+t)*4096 + blk] = s;
    }
}

// ---- cooperative kernel: sB-reduce + 3 sinkhorn iters + assign + accum + proto update
__global__ __launch_bounds__(256) void k_sink(
    const int* __restrict__ gt, const float* __restrict__ expv,
    const float* __restrict__ psb,
    float* __restrict__ uh, float* __restrict__ sk, float* __restrict__ Bc,
    float* __restrict__ pr,
    const float* __restrict__ feat, const float* __restrict__ fg,
    const float* __restrict__ fb,
    const int* __restrict__ cidx, const int* __restrict__ ccnt,
    float* __restrict__ facc, float* __restrict__ ncount,
    float* __restrict__ ptarget,
    const float* __restrict__ pn, float* __restrict__ newp)
{
    cg::grid_group grid = cg::this_grid();
    __shared__ float red[256];
    __shared__ float prodS[2560];
    __shared__ int   gtS[256];
    const int t = threadIdx.x, b = blockIdx.x;

    // phase 0: psb[40][4096] -> Bc, sk
    if (b < 40) {
        float s = 0.f;
        #pragma unroll
        for (int i = 0; i < 16; ++i) s += psb[(size_t)b*4096 + i*256 + t];
        red[t] = s; __syncthreads();
        for (int off = 128; off > 0; off >>= 1) { if (t < off) red[t] += red[t+off]; __syncthreads(); }
        if (t == 0) { if (b < 20) Bc[b] = red[0]; else sk[b-20] = red[0]; }
    }
    grid.sync();

    // 3 sinkhorn iterations
    for (int c = 1; c <= 3; ++c) {
        float acc = 0.f;
        for (int sb = 0; sb < 4; ++sb) {
            int n = b*1024 + sb*256 + t;
            int g = gt[n];
            float e[10];
            {
                const float4* e4 = (const float4*)(expv + (size_t)n*12);
                float4 ea = e4[0], eb = e4[1], ec = e4[2];
                e[0]=ea.x; e[1]=ea.y; e[2]=ea.z; e[3]=ea.w;
                e[4]=eb.x; e[5]=eb.y; e[6]=eb.z; e[7]=eb.w;
                e[8]=ec.x; e[9]=ec.y;
            }
            float skg = sk[g];
            float v = (skg > 0.f) ? 1.f/skg : 1.f;
            float B = Bc[g];
            float Bs = (B > 0.f) ? B : 1.f;
            for (int cc = 1; cc < c; ++cc) {
                const float* uc = uh + (cc-1)*200 + g*10;
                float sc = 0.f;
                #pragma unroll
                for (int m = 0; m < 10; ++m) sc += e[m]*uc[m];
                v = (sc > 0.f) ? 1.f/(Bs*sc) : v/Bs;
            }
            __syncthreads();   // previous sb's prodS reads done
            #pragma unroll
            for (int m = 0; m < 10; ++m) prodS[t*10+m] = e[m]*v;
            gtS[t] = g;
            __syncthreads();
            if (t < 200) {
                int kk = t / 10, mm = t % 10;
                for (int i = 0; i < 256; ++i)
                    if (gtS[i] == kk) acc += prodS[i*10+mm];
            }
        }
        if (t < 200) pr[(size_t)t*256 + b] = acc;
        grid.sync();
        if (b < 200) {
            red[t] = pr[(size_t)b*256 + t]; __syncthreads();
            for (int off = 128; off > 0; off >>= 1) { if (t < off) red[t] += red[t+off]; __syncthreads(); }
            if (t == 0) {
                float S = red[0];
                float uprev = (c == 1) ? 1.f : uh[(c-2)*200 + b];
                uh[(c-1)*200 + b] = (S > 0.f) ? 1.f/(10.f*S) : uprev*0.1f;
            }
        }
        grid.sync();
    }

    // phase C: per-point proto assignment -> ptarget
    const float* u3 = uh + 400;
    for (int sb = 0; sb < 4; ++sb) {
        int n = b*1024 + sb*256 + t;
        int g = gt[n];
        const float* uk = u3 + g*10;
        float bv = -1e30f; int idx = 0;
        #pragma unroll
        for (int m = 0; m < 10; ++m) {
            float pm = expv[(size_t)n*12 + m] * uk[m];
            if (pm > bv) { bv = pm; idx = m; }
        }
        ptarget[n] = (float)(idx + 10*g);
    }

    // phase D: f/ncount accumulation over correct points (wave per point)
    {
        int wid = b*4 + (t >> 6), lane = t & 63;
        int cnt = *ccnt; if (cnt > CCAP) cnt = CCAP;
        for (int i = wid; i < cnt; i += 1024) {
            int n = cidx[i];
            float x0 = feat[(size_t)n*128 + lane], x1 = feat[(size_t)n*128 + 64 + lane];
            float s = x0 + x1;
            #pragma unroll
            for (int off = 32; off > 0; off >>= 1) s += __shfl_xor(s, off);
            float mean = s * (1.f/128.f);
            float d0 = x0 - mean, d1 = x1 - mean;
            float s2 = d0*d0 + d1*d1;
            #pragma unroll
            for (int off = 32; off > 0; off >>= 1) s2 += __shfl_xor(s2, off);
            float rstd = rsqrtf(s2 * (1.f/128.f) + LNEPS);
            float y0 = d0*rstd*fg[lane] + fb[lane];
            float y1 = d1*rstd*fg[64+lane] + fb[64+lane];
            float s3 = y0*y0 + y1*y1;
            #pragma unroll
            for (int off = 32; off > 0; off >>= 1) s3 += __shfl_xor(s3, off);
            float rl2 = 1.f / fmaxf(sqrtf(s3), 1e-12f);
            float c0 = y0*rl2, c1 = y1*rl2;
            int g = gt[n];
            const float* uk = u3 + g*10;
            float bv = -1e30f; int idx = 0;
            #pragma unroll
            for (int m = 0; m < 10; ++m) {
                float pm = expv[(size_t)n*12 + m] * uk[m];
                if (pm > bv) { bv = pm; idx = m; }
            }
            float* frow = facc + (size_t)(g*10+idx)*128;
            atomicAdd(&frow[lane], c0);
            atomicAdd(&frow[64+lane], c1);
            if (lane == 0) atomicAdd(&ncount[g*10+idx], 1.f);
        }
    }
    grid.sync();

    // phase E: momentum update + renormalize (block b -> proto row b)
    if (b < 200 && t < 64) {
        const float OMG = (float)(1.0 - 0.99);
        int j = b, l = t;
        float f0 = facc[(size_t)j*128+l], f1 = facc[(size_t)j*128+64+l];
        float ss = f0*f0 + f1*f1;
        #pragma unroll
        for (int off = 32; off > 0; off >>= 1) ss += __shfl_xor(ss, off);
        float fl2 = fmaxf(sqrtf(ss), 1e-12f);
        float fn0 = f0/fl2, fn1 = f1/fl2;
        float p0 = pn[(size_t)j*128+l], p1 = pn[(size_t)j*128+64+l];
        float u0 = 0.99f*p0 + OMG*fn0, u1 = 0.99f*p1 + OMG*fn1;
        bool ok = ncount[j] > 0.f;
        float sA = ok ? u0 : p0, sB = ok ? u1 : p1;
        float ss2 = sA*sA + sB*sB;
        #pragma unroll
        for (int off = 32; off > 0; off >>= 1) ss2 += __shfl_xor(ss2, off);
        float l2 = fmaxf(sqrtf(ss2), 1e-12f);
        newp[(size_t)j*128+l]      = sA/l2;
        newp[(size_t)j*128+64+l]   = sB/l2;
    }
}

extern "C" void kernel_launch(void* const* d_in, const int* in_sizes, int n_in,
                              void* d_out, int out_size, void* d_ws, size_t ws_size,
                              hipStream_t stream)
{
    const float* feat   = (const float*)d_in[0];
    const int*   gt     = (const int*)  d_in[1];
    const float* protos = (const float*)d_in[2];
    const float* fg     = (const float*)d_in[3];
    const float* fb     = (const float*)d_in[4];
    const float* mg     = (const float*)d_in[5];
    const float* mb     = (const float*)d_in[6];

    float* out      = (float*)d_out;
    float* out_seg  = out;
    float* plog     = out + (size_t)NPTS*20;
    float* ptarget  = out + (size_t)NPTS*220;
    float* newp     = out + (size_t)NPTS*221;

    float* ws   = (float*)d_ws;
    float* pn   = ws + WS_PN;
    _Float16* phi = (_Float16*)(ws + WS_PHI);
    _Float16* plo = (_Float16*)(ws + WS_PLO);
    float* facc = ws + WS_F;
    float* ncnt = ws + WS_NCOUNT;
    int*   ccnt = (int*)(ws + WS_CCNT);
    float* uh   = ws + WS_UH;
    float* sk   = ws + WS_SK;
    float* Bc   = ws + WS_BC;
    float* psb  = ws + WS_PSB;
    float* pr   = ws + WS_PR;
    float* expv = ws + WS_EXPV;
    int*   cidx = (int*)(ws + WS_CIDX);

    // zero facc + ncount + ccnt (contiguous)
    hipMemsetAsync(facc, 0, (25600 + 200 + 8)*sizeof(float), stream);
    hipLaunchKernelGGL(k_norm_protos, dim3(208), dim3(64), 0, stream, protos, pn, phi, plo);
    hipLaunchKernelGGL(k_gemm, dim3(256), dim3(512), 0, stream,
                       feat, phi, plo, fg, fb, plog);
    hipLaunchKernelGGL(k_epi, dim3(4096), dim3(256), 0, stream,
                       plog, gt, mg, mb, out_seg, expv, psb, cidx, ccnt);

    const int* gt_c = gt; const float* expv_c = expv; const float* psb_c = psb;
    const float* feat_c = feat; const float* fg_c = fg; const float* fb_c = fb;
    const int* cidx_c = cidx; const int* ccnt_c = ccnt; const float* pn_c = pn;
    void* args[] = {
        (void*)&gt_c, (void*)&expv_c, (void*)&psb_c,
        (void*)&uh, (void*)&sk, (void*)&Bc, (void*)&pr,
        (void*)&feat_c, (void*)&fg_c, (void*)&fb_c,
        (void*)&cidx_c, (void*)&ccnt_c,
        (void*)&facc, (void*)&ncnt, (void*)&ptarget,
        (void*)&pn_c, (void*)&newp
    };
    hipLaunchCooperativeKernel((void*)k_sink, dim3(256), dim3(256), args, 0, stream);
}